// Round 7
// baseline (17.059 us; speedup 1.0000x reference)
//
#include <hip/hip_runtime.h>
#include <hip/hip_bf16.h>

// Problem constants (fixed by setup_inputs)
#define BB  64      // batches
#define NMM 32      // motifs per batch
#define HH  256     // hidden
#define LFD 16      // ligand feature dim
#define NLA 128     // ligand atoms per batch (NMM*4)

// Softmax over motifs (axis=1) is shift-invariant: protein_rep/residue_rep/
// ligand_rep/b_mlp/b_lig terms are constant per batch row and cancel exactly.
// logit[b,m] (up to a per-batch constant) =
//     emb_table[wid[b,m]] . w4  +  motif_feat_sum[b,m] . (W_lig @ w5)
//
// R3 structure (best measured: 10.37 us). 256 thr/block, one batch per block;
// emb rows straight to registers (8 lanes/motif), roles overlapped, 2 barriers.
// Structural search R4-R6 (fatter lanes / fewer barriers / stacked roles) all
// regressed: this problem is launch-overhead + dependent-gather-latency bound.

__device__ __forceinline__ float dot4(float4 a, float4 b) {
  return a.x * b.x + a.y * b.y + a.z * b.z + a.w * b.w;
}

__global__ __launch_bounds__(256) void score_kernel(
    const float* __restrict__ lig_feat,    // [B*128][16]
    const int*   __restrict__ wids,        // [B*32]
    const float* __restrict__ W_lig,       // [16][256]
    const float* __restrict__ emb_table,   // [501][256]
    const float* __restrict__ W_mlp,       // [1280][1]
    float* __restrict__ out)               // [64*32] vals, then [64*32] idx
{
  const int b    = blockIdx.x;
  const int t    = threadIdx.x;
  const int lane = t & 63;
  const int wave = t >> 6;
  const int m    = wave * 8 + (lane >> 3); // motif this thread's 8-group handles
  const int c    = lane & 7;               // 32-channel chunk within the row

  __shared__ float swl5[LFD];
  __shared__ float slog[NMM];
  __shared__ float st5[NMM];

  // ---- dependent chain first: wid -> emb row chunk (straight to registers) ----
  const int wid = wids[b * NMM + m];
  const float4* er  = (const float4*)(emb_table + (size_t)wid * HH) + c * 8;
  const float4* w4p = (const float4*)(W_mlp + 3 * HH) + c * 8;
  float4 e0 = er[0], e1 = er[1], e2 = er[2], e3 = er[3],
         e4v = er[4], e5 = er[5], e6 = er[6], e7 = er[7];
  float4 w0 = w4p[0], w1 = w4p[1], w2 = w4p[2], w3 = w4p[3],
         w4v = w4p[4], w5v = w4p[5], w6 = w4p[6], w7 = w4p[7];

  // ---- ligand row load (t<128: atom t of this batch) ----
  float4 q0, q1, q2, q3;
  if (t < NLA) {
    const float4* p = (const float4*)(lig_feat + (size_t)(b * NLA + t) * LFD);
    q0 = p[0]; q1 = p[1]; q2 = p[2]; q3 = p[3];
  }

  // ---- swl5[f] = sum_h W_lig[f,h] * w5[h] : 16 threads per f ----
  {
    const int f = t >> 4, h0 = t & 15;
    float s = 0.f;
#pragma unroll
    for (int j = 0; j < 16; ++j)
      s += W_lig[f * HH + h0 + 16 * j] * W_mlp[4 * HH + h0 + 16 * j];
    s += __shfl_xor(s, 1); s += __shfl_xor(s, 2);
    s += __shfl_xor(s, 4); s += __shfl_xor(s, 8);
    if (h0 == 0) swl5[f] = s;
  }

  // ---- motif feature sums in registers (4-lane groups within waves 0,1) ----
  float ms[LFD];
  if (t < NLA) {
    float a[LFD] = {q0.x,q0.y,q0.z,q0.w, q1.x,q1.y,q1.z,q1.w,
                    q2.x,q2.y,q2.z,q2.w, q3.x,q3.y,q3.z,q3.w};
#pragma unroll
    for (int f = 0; f < LFD; ++f) {
      float v = a[f];
      v += __shfl_xor(v, 1); v += __shfl_xor(v, 2);   // 4-atom motif sum
      ms[f] = v;
    }
  }

  // ---- e4[m] = emb_row . w4 : partial over this lane's 32 channels ----
  {
    float s = dot4(e0, w0) + dot4(e1, w1) + dot4(e2, w2) + dot4(e3, w3)
            + dot4(e4v, w4v) + dot4(e5, w5v) + dot4(e6, w6) + dot4(e7, w7);
    s += __shfl_xor(s, 1); s += __shfl_xor(s, 2); s += __shfl_xor(s, 4);
    if (c == 0) slog[m] = s;
  }
  __syncthreads();   // swl5 + slog visible

  // ---- t5[m] = motif_feat_sum . swl5 ----
  if (t < NLA) {
    float t5 = 0.f;
#pragma unroll
    for (int f = 0; f < LFD; ++f) t5 += ms[f] * swl5[f];
    if ((t & 3) == 0) st5[t >> 2] = t5;
  }
  __syncthreads();   // st5 visible

  // ---- softmax + full stable descending rank, entirely in wave 0 ----
  if (t < NMM) {
    const float x = slog[t] + st5[t];
    float mx = x;
    mx = fmaxf(mx, __shfl_xor(mx, 1));
    mx = fmaxf(mx, __shfl_xor(mx, 2));
    mx = fmaxf(mx, __shfl_xor(mx, 4));
    mx = fmaxf(mx, __shfl_xor(mx, 8));
    mx = fmaxf(mx, __shfl_xor(mx, 16));
    const float ex = expf(x - mx);
    float sum = ex;
    sum += __shfl_xor(sum, 1); sum += __shfl_xor(sum, 2);
    sum += __shfl_xor(sum, 4); sum += __shfl_xor(sum, 8);
    sum += __shfl_xor(sum, 16);
    const float sc = ex / sum;
    int rank = 0;
#pragma unroll
    for (int j = 0; j < NMM; ++j) {
      const float sj = __shfl(sc, j);
      rank += (sj > sc) || (sj == sc && j < t);
    }
    out[b * NMM + rank] = sc;                        // vals
    out[BB * NMM + b * NMM + rank] = (float)t;       // idx (as float)
  }
}

extern "C" void kernel_launch(void* const* d_in, const int* in_sizes, int n_in,
                              void* d_out, int out_size, void* d_ws, size_t ws_size,
                              hipStream_t stream) {
  const float* lig_feat    = (const float*)d_in[2];
  const int*   ligand_wids = (const int*)d_in[7];
  const float* W_lig       = (const float*)d_in[14];
  const float* emb_table   = (const float*)d_in[16];
  const float* W_mlp       = (const float*)d_in[18];
  float* out = (float*)d_out;

  score_kernel<<<BB, 256, 0, stream>>>(lig_feat, ligand_wids, W_lig,
                                       emb_table, W_mlp, out);
}